// Round 4
// baseline (289.867 us; speedup 1.0000x reference)
//
#include <hip/hip_runtime.h>

// Gathered skinny GEMM: out[b, r] = sum_d x[b,d] * w[indices[r], d]
//   x: [32][4096] f32, w: [11008][4096] f32, indices: [4403] i32,
//   out: [32][4403] f32
//
// R4: R3 was LDS-pipe-bound: 1 broadcast ds_read_b128 fed only 4 FMAs
// (LDS:VALU cyc = 1536:1024 per kb -> 46us model ~= 55us observed).
// Fix: 2 gathered rows per thread -> each x-read feeds 8 FMAs
// (LDS:VALU = 0.75), LDS hides under the 7.3us VALU floor.
// KSPLIT=64 keeps grid at 576 blocks (2.25 blocks/CU) for latency hiding.
// NOTE: ~190us of reported dur_us is fixed harness overhead (ws poison
// fills at ~109us each + input restore) - kernel budget is the remainder.

#define D_MODEL   4096
#define REMAINED  4403
#define BATCH     32
#define BLOCK     256
#define ROWS_PT   2
#define RBLOCK    (BLOCK * ROWS_PT)                  // 512 rows per block
#define RTILES    ((REMAINED + RBLOCK - 1) / RBLOCK) // 9
#define RSLOTS    (RTILES * RBLOCK)                  // 4608
#define KSPLIT    64
#define KCHUNK    (D_MODEL / KSPLIT)                 // 64 floats
#define K4CHUNK   (KCHUNK / 4)                       // 16 float4
#define GRID1     (RTILES * KSPLIT)                  // 576 blocks

__global__ __launch_bounds__(BLOCK) void gather_gemv_p1(
    const float* __restrict__ x,
    const float* __restrict__ w,
    const int*   __restrict__ idx,
    float*       __restrict__ partial)
{
    __shared__ float4 xs4[BATCH * K4CHUNK];          // [b][kk], 8 KB

    const int rt = blockIdx.x % RTILES;
    const int ks = blockIdx.x / RTILES;

    // --- stage x chunk: 512 float4, 2 per thread, coalesced ---
    {
        const float4* __restrict__ xg4 = (const float4*)x;  // [b][1024]
#pragma unroll
        for (int u = 0; u < (BATCH * K4CHUNK) / BLOCK; ++u) {   // 2
            const int v  = u * BLOCK + (int)threadIdx.x;
            const int b  = v / K4CHUNK;
            const int kk = v % K4CHUNK;
            xs4[v] = xg4[(size_t)b * (D_MODEL / 4) + ks * K4CHUNK + kk];
        }
    }

    // row setup before the barrier so idx load overlaps staging
    const int  r0 = rt * RBLOCK + (int)threadIdx.x;
    const int  r1 = r0 + BLOCK;
    const bool a0 = (r0 < REMAINED);
    const bool a1 = (r1 < REMAINED);
    const int  row0 = idx[a0 ? r0 : (REMAINED - 1)];
    const int  row1 = idx[a1 ? r1 : (REMAINED - 1)];

    const float4* __restrict__ wp0 =
        (const float4*)(w + (size_t)row0 * D_MODEL) + ks * K4CHUNK;
    const float4* __restrict__ wp1 =
        (const float4*)(w + (size_t)row1 * D_MODEL) + ks * K4CHUNK;

    __syncthreads();

    float acc0[BATCH], acc1[BATCH];
#pragma unroll
    for (int b = 0; b < BATCH; ++b) { acc0[b] = 0.f; acc1[b] = 0.f; }

    // --- K loop: 4 groups of 4 float4 (64 B/lane/row = full cacheline) ---
    float4 wa0 = wp0[0], wa1 = wp0[1], wa2 = wp0[2], wa3 = wp0[3];
    float4 wb0 = wp1[0], wb1 = wp1[1], wb2 = wp1[2], wb3 = wp1[3];

#pragma unroll
    for (int kb = 0; kb < K4CHUNK / 4; ++kb) {
        // prefetch next group (clamped on last iter: L1-hit re-load, harmless)
        const int nkb = (kb < K4CHUNK / 4 - 1) ? (kb + 1) : kb;
        float4 na0 = wp0[nkb * 4 + 0], na1 = wp0[nkb * 4 + 1];
        float4 na2 = wp0[nkb * 4 + 2], na3 = wp0[nkb * 4 + 3];
        float4 nb0 = wp1[nkb * 4 + 0], nb1 = wp1[nkb * 4 + 1];
        float4 nb2 = wp1[nkb * 4 + 2], nb3 = wp1[nkb * 4 + 3];

        const float4 wra[4] = { wa0, wa1, wa2, wa3 };
        const float4 wrb[4] = { wb0, wb1, wb2, wb3 };
#pragma unroll
        for (int u = 0; u < 4; ++u) {
#pragma unroll
            for (int b = 0; b < BATCH; ++b) {
                // one broadcast LDS read feeds BOTH rows (8 FMAs)
                const float4 xv = xs4[b * K4CHUNK + kb * 4 + u];
                acc0[b] = fmaf(wra[u].x, xv.x, acc0[b]);
                acc0[b] = fmaf(wra[u].y, xv.y, acc0[b]);
                acc0[b] = fmaf(wra[u].z, xv.z, acc0[b]);
                acc0[b] = fmaf(wra[u].w, xv.w, acc0[b]);
                acc1[b] = fmaf(wrb[u].x, xv.x, acc1[b]);
                acc1[b] = fmaf(wrb[u].y, xv.y, acc1[b]);
                acc1[b] = fmaf(wrb[u].z, xv.z, acc1[b]);
                acc1[b] = fmaf(wrb[u].w, xv.w, acc1[b]);
            }
        }
        wa0 = na0; wa1 = na1; wa2 = na2; wa3 = na3;
        wb0 = nb0; wb1 = nb1; wb2 = nb2; wb3 = nb3;
    }

    // --- store partial tiles (padded rows store 0), wave-coalesced ---
    if (!a0) {
#pragma unroll
        for (int b = 0; b < BATCH; ++b) acc0[b] = 0.f;
    }
    if (!a1) {
#pragma unroll
        for (int b = 0; b < BATCH; ++b) acc1[b] = 0.f;
    }
    float* p = partial + (size_t)ks * BATCH * RSLOTS;
#pragma unroll
    for (int b = 0; b < BATCH; ++b) {
        p[(size_t)b * RSLOTS + r0] = acc0[b];
        p[(size_t)b * RSLOTS + r1] = acc1[b];
    }
}

// Phase 2: out[b][r] = sum_ks partial[ks][b][r]  (partials are L3-resident)
#define GRID2  ((BATCH * (RSLOTS / 4)) / BLOCK)      // 32*1152/256 = 144

__global__ __launch_bounds__(BLOCK) void gather_gemv_p2(
    const float* __restrict__ partial,
    float*       __restrict__ out)
{
    const int g  = blockIdx.x * BLOCK + threadIdx.x;
    const int b  = g / (RSLOTS / 4);
    const int r4 = g % (RSLOTS / 4);

    const float4* p = (const float4*)(partial) + ((size_t)b * (RSLOTS / 4) + r4);

    float4 s = make_float4(0.f, 0.f, 0.f, 0.f);
#pragma unroll
    for (int ks = 0; ks < KSPLIT; ++ks) {
        const float4 v = p[(size_t)ks * BATCH * (RSLOTS / 4)];
        s.x += v.x; s.y += v.y; s.z += v.z; s.w += v.w;
    }

    const int r0 = r4 * 4;
    float* o = out + (size_t)b * REMAINED;
    if (r0 + 3 < REMAINED) {
        o[r0 + 0] = s.x; o[r0 + 1] = s.y; o[r0 + 2] = s.z; o[r0 + 3] = s.w;
    } else {
        if (r0 + 0 < REMAINED) o[r0 + 0] = s.x;
        if (r0 + 1 < REMAINED) o[r0 + 1] = s.y;
        if (r0 + 2 < REMAINED) o[r0 + 2] = s.z;
        if (r0 + 3 < REMAINED) o[r0 + 3] = s.w;
    }
}

extern "C" void kernel_launch(void* const* d_in, const int* in_sizes, int n_in,
                              void* d_out, int out_size, void* d_ws, size_t ws_size,
                              hipStream_t stream) {
    const float* x   = (const float*)d_in[0];
    const float* w   = (const float*)d_in[1];
    const int*   idx = (const int*)d_in[2];
    float*       out = (float*)d_out;
    float*       ws  = (float*)d_ws;

    gather_gemv_p1<<<GRID1, BLOCK, 0, stream>>>(x, w, idx, ws);
    gather_gemv_p2<<<GRID2, BLOCK, 0, stream>>>(ws, out);
}

// Round 5
// 237.880 us; speedup vs baseline: 1.2185x; 1.2185x over previous
//
#include <hip/hip_runtime.h>
#include <hip/hip_bf16.h>

// Gathered skinny GEMM: out[b, r] = sum_d x[b,d] * w[indices[r], d]
//   x: [32][4096] f32, w: [11008][4096] f32, indices: [4403] i32,
//   out: [32][4403] f32
//
// R5: abandon the fp32-VALU structure (R2-R4 all latency/scheduler-bound at
// 50-110us vs 7.3us VALU floor). bf16 MFMA is numerically admissible
// (est. error ~0.01-0.03 << 0.122 threshold) and makes compute free
// (~0.5us), leaving pure HBM roofline: ~60-72 MB gathered W @ 6.3 TB/s
// ~= 10-12us. No LDS: MFMA fragments load straight from global.
//   A = gathered W rows (M=16 r's/tile): lane(quad=l>>4, m=l&15) loads
//       W[idx[rt*16+m]][k0 + quad*8 + 0..7] = 32 B contiguous, cvt->bf16.
//   B = x_bf16 (pre-converted, 256 KB, L2-resident): 16 B contiguous/lane.
//   D: lane holds D[m=quad*4+reg][n=lane&15] -> 4 consecutive r's per b,
//       one float4 store per b-tile. (Layouts per m89/m91/m120.)
// KSPLIT=16 -> 4416 waves (4.3/SIMD); partials (9 MB) reduced by p2.

#define D_MODEL   4096
#define REMAINED  4403
#define BATCH     32
#define KSPLIT    16
#define KCHUNK    (D_MODEL / KSPLIT)      // 256 floats
#define KSTEPS    (KCHUNK / 32)           // 8 MFMA k-steps per wave
#define RT16      ((REMAINED + 15) / 16)  // 276 r-tiles
#define RSLOTS    (RT16 * 16)             // 4416 padded rows
#define BLOCK     256
#define GRID1     ((RT16 * KSPLIT) / 4)   // 4416 waves / 4 per block = 1104

typedef __attribute__((ext_vector_type(8))) short  short8;   // 8 bf16
typedef __attribute__((ext_vector_type(4))) float  floatx4;  // 4 fp32 acc

// ws layout: [0, 256KB)            x_bf16 [32][4096]
//            [256KB, 256KB+9.04MB) partial [KSPLIT][BATCH][RSLOTS] fp32
#define XB_ELEMS   (BATCH * D_MODEL)                 // 131072
#define PART_OFF   (XB_ELEMS * 2)                    // bytes: 256 KB

// ---- p0: convert x to bf16 (RNE) ------------------------------------
__global__ __launch_bounds__(BLOCK) void p0_cvt(
    const float* __restrict__ x, __hip_bfloat16* __restrict__ xb)
{
    const int i = blockIdx.x * BLOCK + threadIdx.x;  // 0..32767, 4 floats each
    const float4 v = ((const float4*)x)[i];
    __hip_bfloat162* o = (__hip_bfloat162*)xb;
    o[2 * i + 0] = __float22bfloat162_rn(make_float2(v.x, v.y));
    o[2 * i + 1] = __float22bfloat162_rn(make_float2(v.z, v.w));
}

// ---- p1: gathered MFMA GEMM, split-K partials -----------------------
union ABFrag { short8 s8; __hip_bfloat162 h2[4]; };

__global__ __launch_bounds__(BLOCK) void p1_mfma(
    const float* __restrict__ w,
    const int*   __restrict__ idx,
    const __hip_bfloat16* __restrict__ xb,
    float*       __restrict__ partial)
{
    const int wid  = blockIdx.x * 4 + ((int)threadIdx.x >> 6);
    const int lane = (int)threadIdx.x & 63;
    const int quad = lane >> 4;
    const int m    = lane & 15;

    const int rt = wid % RT16;
    const int ks = wid / RT16;

    // gathered W row for this lane's A-fragment rows
    const int r  = rt * 16 + m;
    const int rc = (r < REMAINED) ? r : (REMAINED - 1);  // padded rows: garbage,
    const int row = idx[rc];                             // masked out in p2

    // per step s: lane reads W[row][ks*KCHUNK + s*32 + quad*8 + 0..7]
    const float4* __restrict__ wp =
        (const float4*)(w + (size_t)row * D_MODEL + ks * KCHUNK) + quad * 2;

    // B fragments: x_bf16[b][ks*KCHUNK + s*32 + quad*8 + 0..7], b-tiles m / m+16
    const short8* __restrict__ xp0 =
        (const short8*)(xb + (size_t)m * D_MODEL + ks * KCHUNK) + quad;
    const short8* __restrict__ xp1 =
        (const short8*)(xb + (size_t)(m + 16) * D_MODEL + ks * KCHUNK) + quad;

    floatx4 acc0 = {0.f, 0.f, 0.f, 0.f};
    floatx4 acc1 = {0.f, 0.f, 0.f, 0.f};

#pragma unroll
    for (int s = 0; s < KSTEPS; ++s) {
        const float4 w0 = wp[s * 8 + 0];
        const float4 w1 = wp[s * 8 + 1];
        const short8 b0 = xp0[s * 4];
        const short8 b1 = xp1[s * 4];

        ABFrag af;
        af.h2[0] = __float22bfloat162_rn(make_float2(w0.x, w0.y));
        af.h2[1] = __float22bfloat162_rn(make_float2(w0.z, w0.w));
        af.h2[2] = __float22bfloat162_rn(make_float2(w1.x, w1.y));
        af.h2[3] = __float22bfloat162_rn(make_float2(w1.z, w1.w));

        acc0 = __builtin_amdgcn_mfma_f32_16x16x32_bf16(af.s8, b0, acc0, 0, 0, 0);
        acc1 = __builtin_amdgcn_mfma_f32_16x16x32_bf16(af.s8, b1, acc1, 0, 0, 0);
    }

    // D[m'=quad*4+reg][n=lane&15]: lane holds 4 consecutive r's for batch n.
    // partial[ks][b][rslot]
    const int rbase = rt * 16 + quad * 4;
    float* pa = partial + ((size_t)(ks * BATCH + m) * RSLOTS + rbase);
    float* pb = partial + ((size_t)(ks * BATCH + m + 16) * RSLOTS + rbase);
    *(float4*)pa = make_float4(acc0[0], acc0[1], acc0[2], acc0[3]);
    *(float4*)pb = make_float4(acc1[0], acc1[1], acc1[2], acc1[3]);
}

// ---- p2: reduce KSPLIT planes, masked write -------------------------
#define GRID2  ((BATCH * (RSLOTS / 4)) / BLOCK)      // 32*1104/256 = 138

__global__ __launch_bounds__(BLOCK) void p2_reduce(
    const float* __restrict__ partial,
    float*       __restrict__ out)
{
    const int g  = blockIdx.x * BLOCK + threadIdx.x;  // 0..35327
    const int b  = g / (RSLOTS / 4);
    const int r4 = g % (RSLOTS / 4);

    const float4* p = (const float4*)partial + ((size_t)b * (RSLOTS / 4) + r4);

    float4 s = make_float4(0.f, 0.f, 0.f, 0.f);
#pragma unroll
    for (int ks = 0; ks < KSPLIT; ++ks) {
        const float4 v = p[(size_t)ks * BATCH * (RSLOTS / 4)];
        s.x += v.x; s.y += v.y; s.z += v.z; s.w += v.w;
    }

    const int r0 = r4 * 4;
    float* o = out + (size_t)b * REMAINED;
    if (r0 + 3 < REMAINED) {
        *(float4*)(o + r0) = s;
    } else {
        if (r0 + 0 < REMAINED) o[r0 + 0] = s.x;
        if (r0 + 1 < REMAINED) o[r0 + 1] = s.y;
        if (r0 + 2 < REMAINED) o[r0 + 2] = s.z;
        if (r0 + 3 < REMAINED) o[r0 + 3] = s.w;
    }
}

extern "C" void kernel_launch(void* const* d_in, const int* in_sizes, int n_in,
                              void* d_out, int out_size, void* d_ws, size_t ws_size,
                              hipStream_t stream) {
    const float* x   = (const float*)d_in[0];
    const float* w   = (const float*)d_in[1];
    const int*   idx = (const int*)d_in[2];
    float*       out = (float*)d_out;

    __hip_bfloat16* xb      = (__hip_bfloat16*)d_ws;
    float*          partial = (float*)((char*)d_ws + PART_OFF);

    p0_cvt   <<<XB_ELEMS / 4 / BLOCK, BLOCK, 0, stream>>>(x, xb);   // 128 blocks
    p1_mfma  <<<GRID1, BLOCK, 0, stream>>>(w, idx, xb, partial);
    p2_reduce<<<GRID2, BLOCK, 0, stream>>>(partial, out);
}